// Round 1
// baseline (446.621 us; speedup 1.0000x reference)
//
#include <hip/hip_runtime.h>

typedef unsigned short u16;
typedef __attribute__((ext_vector_type(8))) short bf16x8;
typedef __attribute__((ext_vector_type(4))) float f32x4;

#define GLDS16(g, l)                                                        \
  __builtin_amdgcn_global_load_lds(                                         \
      (const __attribute__((address_space(1))) void*)(g),                   \
      (__attribute__((address_space(3))) void*)(l), 16, 0, 0)

__device__ __forceinline__ u16 f2bf(float f) {
  union { float f; unsigned u; } v; v.f = f;
  unsigned r = v.u + 0x7FFFu + ((v.u >> 16) & 1u);
  return (u16)(r >> 16);
}

// ---------------- f32 -> bf16 conversion (exact grid, n % 1024 == 0) -----
__global__ __launch_bounds__(256) void cvt_kernel(const float4* __restrict__ in,
                                                  ushort4* __restrict__ out) {
  int i = blockIdx.x * 256 + threadIdx.x;
  float4 v = in[i];
  ushort4 o;
  o.x = f2bf(v.x); o.y = f2bf(v.y); o.z = f2bf(v.z); o.w = f2bf(v.w);
  out[i] = o;
}

// ---------------- NT GEMM core: C[m,n] = sum_k A[m,k] * W[n,k] -----------
// A: M x 1024 bf16 row-major. W: N x 1024 bf16 row-major (i.e. x @ W.T).
// MODE 0: store bf16 head-split (B,H,S,D).  MODE 1: store f32 row-major.
template <int MODE>
__device__ __forceinline__ void gemm_core(const u16* __restrict__ A,
                                          const u16* __restrict__ W,
                                          void* __restrict__ C) {
  const int K = 1024;
  __shared__ u16 lds_a[4096];  // 128 rows x 32 cols bf16 (64 B/row)
  __shared__ u16 lds_b[4096];
  const int bn = blockIdx.x, bm = blockIdx.y;
  const int tid = threadIdx.x, l = tid & 63, wid = tid >> 6;
  const int wr = wid >> 1, wc = wid & 1;
  const int l4 = l >> 4, l15 = l & 15;

  f32x4 zero4 = {0.f, 0.f, 0.f, 0.f};
  f32x4 acc[4][4];
  for (int i = 0; i < 4; ++i)
    for (int j = 0; j < 4; ++j) acc[i][j] = zero4;

  const int srow = tid >> 2, scol = (tid & 3) * 8;
  const u16* Ag = A + (bm * 128 + srow) * K + scol;
  const u16* Wg = W + (bn * 128 + srow) * K + scol;
  // wave-uniform LDS staging base; HW writes base + lane*16
  char* la = (char*)lds_a + wid * 1024;
  char* lb = (char*)lds_b + wid * 1024;

  for (int kt = 0; kt < K; kt += 32) {
    GLDS16(Ag + kt, la);
    GLDS16(Ag + 64 * K + kt, la + 4096);
    GLDS16(Wg + kt, lb);
    GLDS16(Wg + 64 * K + kt, lb + 4096);
    __syncthreads();
    bf16x8 af[4], bf[4];
    for (int i = 0; i < 4; ++i)
      af[i] = *(const bf16x8*)((const char*)lds_a +
                               (wr * 64 + i * 16 + l15) * 64 + l4 * 16);
    for (int j = 0; j < 4; ++j)
      bf[j] = *(const bf16x8*)((const char*)lds_b +
                               (wc * 64 + j * 16 + l15) * 64 + l4 * 16);
    for (int i = 0; i < 4; ++i)
      for (int j = 0; j < 4; ++j)
        acc[i][j] = __builtin_amdgcn_mfma_f32_16x16x32_bf16(af[i], bf[j],
                                                            acc[i][j], 0, 0, 0);
    __syncthreads();
  }

  for (int i = 0; i < 4; ++i)
    for (int j = 0; j < 4; ++j) {
      f32x4 a = acc[i][j];
      for (int r = 0; r < 4; ++r) {
        int m = bm * 128 + wr * 64 + i * 16 + l4 * 4 + r;
        int n = bn * 128 + wc * 64 + j * 16 + l15;
        if (MODE == 0) {
          int bb = m >> 11, srw = m & 2047, h = n >> 6, d = n & 63;
          ((u16*)C)[((bb * 16 + h) * 2048 + srw) * 64 + d] = f2bf(a[r]);
        } else {
          ((float*)C)[m * 1024 + n] = a[r];
        }
      }
    }
}

__global__ __launch_bounds__(256) void gemm_proj(
    const u16* __restrict__ X0, const u16* __restrict__ X1,
    const u16* __restrict__ X2, const u16* __restrict__ W0,
    const u16* __restrict__ W1, const u16* __restrict__ W2,
    u16* __restrict__ O0, u16* __restrict__ O1, u16* __restrict__ O2) {
  int z = blockIdx.z;
  const u16* A = (z == 0) ? X0 : (z == 1) ? X1 : X2;
  const u16* W = (z == 0) ? W0 : (z == 1) ? W1 : W2;
  u16* O = (z == 0) ? O0 : (z == 1) ? O1 : O2;
  gemm_core<0>(A, W, (void*)O);
}

__global__ __launch_bounds__(256) void gemm_out(const u16* __restrict__ A,
                                                const u16* __restrict__ W,
                                                float* __restrict__ C) {
  gemm_core<1>(A, W, (void*)C);
}

// ---------------- V (B,H,S,D) -> V^T (B,H,D,S) ---------------------------
__global__ __launch_bounds__(256) void transpose_v(const u16* __restrict__ Vp,
                                                   u16* __restrict__ Vt) {
  const int st = blockIdx.x, bh = blockIdx.y;
  const int d = threadIdx.x & 63, sg = threadIdx.x >> 6;
  const u16* src = Vp + bh * 131072;
  u16* dst = Vt + bh * 131072;
  const int s0 = st * 64 + sg * 16;
  u16 tmp[16];
  for (int i = 0; i < 16; ++i) tmp[i] = src[(s0 + i) * 64 + d];
  ushort4* o = (ushort4*)(dst + d * 2048 + s0);
  for (int k = 0; k < 4; ++k) {
    ushort4 t4;
    t4.x = tmp[4 * k]; t4.y = tmp[4 * k + 1];
    t4.z = tmp[4 * k + 2]; t4.w = tmp[4 * k + 3];
    o[k] = t4;
  }
}

// ---------------- causal flash attention ---------------------------------
// Qp,Kp: (B,H,S,D) bf16; Vt: (B,H,D,S) bf16; ctx out: (B*S, 1024) bf16
__global__ __launch_bounds__(256) void attn_kernel(const u16* __restrict__ Qp,
                                                   const u16* __restrict__ Kp,
                                                   const u16* __restrict__ Vt,
                                                   u16* __restrict__ ctx) {
  const int qt = blockIdx.x, bh = blockIdx.y;
  const int tid = threadIdx.x, w = tid >> 6, l = tid & 63;
  const int l4 = l >> 4, l15 = l & 15;
  __shared__ u16 lds_p[4][1024];  // per-wave 16x64 P tile, XOR-swizzled

  const int q0 = qt * 64 + w * 16;
  const u16* qbase = Qp + (bh * 2048 + q0 + l15) * 64 + l4 * 8;
  bf16x8 aq0 = *(const bf16x8*)(qbase);
  bf16x8 aq1 = *(const bf16x8*)(qbase + 32);

  f32x4 zero4 = {0.f, 0.f, 0.f, 0.f};
  f32x4 accO[4];
  for (int g = 0; g < 4; ++g) accO[g] = zero4;
  float mrow[4], lrow[4], alpha[4];
  for (int r = 0; r < 4; ++r) { mrow[r] = -__builtin_inff(); lrow[r] = 0.f; }

  char* pw = (char*)lds_p[w];

  for (int t2 = 0; t2 <= qt; ++t2) {
    const int kv0 = t2 * 64;
    // ---- S = Q K^T ----
    f32x4 s[4];
    for (int g = 0; g < 4; ++g) s[g] = zero4;
    const u16* kb = Kp + (bh * 2048 + kv0 + l15) * 64 + l4 * 8;
    for (int g = 0; g < 4; ++g) {
      bf16x8 bk = *(const bf16x8*)(kb + g * 1024);
      s[g] = __builtin_amdgcn_mfma_f32_16x16x32_bf16(aq0, bk, s[g], 0, 0, 0);
    }
    for (int g = 0; g < 4; ++g) {
      bf16x8 bk = *(const bf16x8*)(kb + g * 1024 + 32);
      s[g] = __builtin_amdgcn_mfma_f32_16x16x32_bf16(aq1, bk, s[g], 0, 0, 0);
    }
    // ---- scale + causal mask (exactly -100000 above diag, like ref) ----
    float sv[4][4];
    const bool diag = (t2 == qt);
    for (int g = 0; g < 4; ++g)
      for (int r = 0; r < 4; ++r) {
        float v = s[g][r] * 0.03125f;
        if (diag) {
          int j = kv0 + g * 16 + l15;
          int qg = q0 + l4 * 4 + r;
          if (j > qg) v -= 100000.f;
        }
        sv[g][r] = v;
      }
    // ---- online softmax (row stats across 16 lanes) ----
    for (int r = 0; r < 4; ++r) {
      float mx = fmaxf(fmaxf(sv[0][r], sv[1][r]), fmaxf(sv[2][r], sv[3][r]));
      mx = fmaxf(mx, __shfl_xor(mx, 1));
      mx = fmaxf(mx, __shfl_xor(mx, 2));
      mx = fmaxf(mx, __shfl_xor(mx, 4));
      mx = fmaxf(mx, __shfl_xor(mx, 8));
      float mn = fmaxf(mrow[r], mx);
      alpha[r] = __expf(mrow[r] - mn);
      mrow[r] = mn;
      float rs = 0.f;
      for (int g = 0; g < 4; ++g) {
        float p = __expf(sv[g][r] - mn);
        sv[g][r] = p;
        rs += p;
      }
      rs += __shfl_xor(rs, 1);
      rs += __shfl_xor(rs, 2);
      rs += __shfl_xor(rs, 4);
      rs += __shfl_xor(rs, 8);
      lrow[r] = lrow[r] * alpha[r] + rs;
    }
    for (int g = 0; g < 4; ++g) {
      f32x4 t = accO[g];
      t[0] *= alpha[0]; t[1] *= alpha[1]; t[2] *= alpha[2]; t[3] *= alpha[3];
      accO[g] = t;
    }
    // ---- P -> LDS (bf16, XOR swizzle: byte ^= (row&7)<<4) ----
    for (int g = 0; g < 4; ++g)
      for (int r = 0; r < 4; ++r) {
        int row = l4 * 4 + r;
        int byte = (row * 128 + (g * 16 + l15) * 2) ^ ((row & 7) << 4);
        *(u16*)(pw + byte) = f2bf(sv[g][r]);
      }
    __syncthreads();
    bf16x8 pa0, pa1;
    {
      int row = l15;
      int b0 = (row * 128 + l4 * 16) ^ ((row & 7) << 4);
      int b1 = (row * 128 + 64 + l4 * 16) ^ ((row & 7) << 4);
      pa0 = *(const bf16x8*)(pw + b0);
      pa1 = *(const bf16x8*)(pw + b1);
    }
    // ---- O += P V ----
    const u16* vb = Vt + (bh * 64 + l15) * 2048 + kv0 + l4 * 8;
    for (int g = 0; g < 4; ++g) {
      bf16x8 bv = *(const bf16x8*)(vb + g * 16 * 2048);
      accO[g] = __builtin_amdgcn_mfma_f32_16x16x32_bf16(pa0, bv, accO[g], 0, 0, 0);
    }
    for (int g = 0; g < 4; ++g) {
      bf16x8 bv = *(const bf16x8*)(vb + g * 16 * 2048 + 32);
      accO[g] = __builtin_amdgcn_mfma_f32_16x16x32_bf16(pa1, bv, accO[g], 0, 0, 0);
    }
    __syncthreads();
  }
  // ---- epilogue: ctx[b*2048+s][h*64+d] = O / l ----
  const int b = bh >> 4, h = bh & 15;
  for (int r = 0; r < 4; ++r) {
    float inv = 1.f / lrow[r];
    int srow = q0 + l4 * 4 + r;
    u16* orow = ctx + (b * 2048 + srow) * 1024 + h * 64;
    for (int g = 0; g < 4; ++g) orow[g * 16 + l15] = f2bf(accO[g][r] * inv);
  }
}

extern "C" void kernel_launch(void* const* d_in, const int* in_sizes, int n_in,
                              void* d_out, int out_size, void* d_ws,
                              size_t ws_size, hipStream_t stream) {
  (void)in_sizes; (void)n_in; (void)out_size; (void)ws_size;
  const float* key = (const float*)d_in[0];
  const float* query = (const float*)d_in[1];
  const float* value = (const float*)d_in[2];
  const float* Wk = (const float*)d_in[3];
  const float* Wq = (const float*)d_in[4];
  const float* Wv = (const float*)d_in[5];
  const float* Wo = (const float*)d_in[6];

  char* ws = (char*)d_ws;
  u16* keyb = (u16*)(ws + 0);          // 4096x1024 bf16
  u16* qryb = (u16*)(ws + 8388608);
  u16* valb = (u16*)(ws + 16777216);
  u16* Wkb  = (u16*)(ws + 25165824);   // 1024x1024 bf16 each
  u16* Wqb  = (u16*)(ws + 27262976);
  u16* Wvb  = (u16*)(ws + 29360128);
  u16* Wob  = (u16*)(ws + 31457280);
  u16* Kp   = (u16*)(ws + 33554432);   // (B,H,S,D) bf16
  u16* Qp   = (u16*)(ws + 41943040);
  u16* Vp   = (u16*)(ws + 50331648);
  u16* Vt   = (u16*)(ws + 58720256);   // (B,H,D,S) bf16
  u16* ctx  = (u16*)(ws + 67108864);   // (B*S, 1024) bf16

  cvt_kernel<<<4096, 256, 0, stream>>>((const float4*)key, (ushort4*)keyb);
  cvt_kernel<<<4096, 256, 0, stream>>>((const float4*)query, (ushort4*)qryb);
  cvt_kernel<<<4096, 256, 0, stream>>>((const float4*)value, (ushort4*)valb);
  cvt_kernel<<<1024, 256, 0, stream>>>((const float4*)Wk, (ushort4*)Wkb);
  cvt_kernel<<<1024, 256, 0, stream>>>((const float4*)Wq, (ushort4*)Wqb);
  cvt_kernel<<<1024, 256, 0, stream>>>((const float4*)Wv, (ushort4*)Wvb);
  cvt_kernel<<<1024, 256, 0, stream>>>((const float4*)Wo, (ushort4*)Wob);

  gemm_proj<<<dim3(8, 32, 3), 256, 0, stream>>>(keyb, qryb, valb, Wkb, Wqb,
                                                Wvb, Kp, Qp, Vp);
  transpose_v<<<dim3(32, 32), 256, 0, stream>>>(Vp, Vt);
  attn_kernel<<<dim3(32, 32), 256, 0, stream>>>(Qp, Kp, Vt, ctx);
  gemm_out<<<dim3(8, 32), 256, 0, stream>>>(ctx, Wob, (float*)d_out);
}

// Round 4
// 312.607 us; speedup vs baseline: 1.4287x; 1.4287x over previous
//
#include <hip/hip_runtime.h>
#include <hip/hip_bf16.h>

typedef unsigned short u16;
typedef __attribute__((ext_vector_type(8))) short bf16x8;
typedef __attribute__((ext_vector_type(4))) float f32x4;

#define GLDS16(g, l)                                                        \
  __builtin_amdgcn_global_load_lds(                                         \
      (const __attribute__((address_space(1))) void*)(g),                   \
      (__attribute__((address_space(3))) void*)(l), 16, 0, 0)

__device__ __forceinline__ u16 f2bf(float f) {
  union { float f; unsigned u; } v; v.f = f;
  unsigned r = v.u + 0x7FFFu + ((v.u >> 16) & 1u);
  return (u16)(r >> 16);
}

// ---------------- f32 -> bf16 conversion (exact grid, n % 1024 == 0) -----
__global__ __launch_bounds__(256) void cvt_kernel(const float4* __restrict__ in,
                                                  ushort4* __restrict__ out) {
  int i = blockIdx.x * 256 + threadIdx.x;
  float4 v = in[i];
  ushort4 o;
  o.x = f2bf(v.x); o.y = f2bf(v.y); o.z = f2bf(v.z); o.w = f2bf(v.w);
  out[i] = o;
}

// ---------------- NT GEMM core: C[m,n] = sum_k A[m,k] * W[n,k] -----------
template <int MODE>
__device__ __forceinline__ void gemm_core(const u16* __restrict__ A,
                                          const u16* __restrict__ W,
                                          void* __restrict__ C) {
  const int K = 1024;
  __shared__ u16 lds_a[4096];  // 128 rows x 32 cols bf16 (64 B/row)
  __shared__ u16 lds_b[4096];
  const int bn = blockIdx.x, bm = blockIdx.y;
  const int tid = threadIdx.x, l = tid & 63, wid = tid >> 6;
  const int wr = wid >> 1, wc = wid & 1;
  const int l4 = l >> 4, l15 = l & 15;

  f32x4 zero4 = {0.f, 0.f, 0.f, 0.f};
  f32x4 acc[4][4];
  for (int i = 0; i < 4; ++i)
    for (int j = 0; j < 4; ++j) acc[i][j] = zero4;

  const int srow = tid >> 2, scol = (tid & 3) * 8;
  const u16* Ag = A + (bm * 128 + srow) * K + scol;
  const u16* Wg = W + (bn * 128 + srow) * K + scol;
  char* la = (char*)lds_a + wid * 1024;
  char* lb = (char*)lds_b + wid * 1024;

  for (int kt = 0; kt < K; kt += 32) {
    GLDS16(Ag + kt, la);
    GLDS16(Ag + 64 * K + kt, la + 4096);
    GLDS16(Wg + kt, lb);
    GLDS16(Wg + 64 * K + kt, lb + 4096);
    __syncthreads();
    bf16x8 af[4], bf[4];
    for (int i = 0; i < 4; ++i)
      af[i] = *(const bf16x8*)((const char*)lds_a +
                               (wr * 64 + i * 16 + l15) * 64 + l4 * 16);
    for (int j = 0; j < 4; ++j)
      bf[j] = *(const bf16x8*)((const char*)lds_b +
                               (wc * 64 + j * 16 + l15) * 64 + l4 * 16);
    for (int i = 0; i < 4; ++i)
      for (int j = 0; j < 4; ++j)
        acc[i][j] = __builtin_amdgcn_mfma_f32_16x16x32_bf16(af[i], bf[j],
                                                            acc[i][j], 0, 0, 0);
    __syncthreads();
  }

  for (int i = 0; i < 4; ++i)
    for (int j = 0; j < 4; ++j) {
      f32x4 a = acc[i][j];
      for (int r = 0; r < 4; ++r) {
        int m = bm * 128 + wr * 64 + i * 16 + l4 * 4 + r;
        int n = bn * 128 + wc * 64 + j * 16 + l15;
        if (MODE == 0) {
          int bb = m >> 11, srw = m & 2047, h = n >> 6, d = n & 63;
          ((u16*)C)[((bb * 16 + h) * 2048 + srw) * 64 + d] = f2bf(a[r]);
        } else {
          ((float*)C)[m * 1024 + n] = a[r];
        }
      }
    }
}

__global__ __launch_bounds__(256) void gemm_proj(
    const u16* __restrict__ X0, const u16* __restrict__ X1,
    const u16* __restrict__ X2, const u16* __restrict__ W0,
    const u16* __restrict__ W1, const u16* __restrict__ W2,
    u16* __restrict__ O0, u16* __restrict__ O1, u16* __restrict__ O2) {
  int z = blockIdx.z;
  const u16* A = (z == 0) ? X0 : (z == 1) ? X1 : X2;
  const u16* W = (z == 0) ? W0 : (z == 1) ? W1 : W2;
  u16* O = (z == 0) ? O0 : (z == 1) ? O1 : O2;
  gemm_core<0>(A, W, (void*)O);
}

__global__ __launch_bounds__(256) void gemm_out(const u16* __restrict__ A,
                                                const u16* __restrict__ W,
                                                float* __restrict__ C) {
  gemm_core<1>(A, W, (void*)C);
}

// ---------------- V (B,H,S,D) -> V^T (B,H,D,S) ---------------------------
__global__ __launch_bounds__(256) void transpose_v(const u16* __restrict__ Vp,
                                                   u16* __restrict__ Vt) {
  const int st = blockIdx.x, bh = blockIdx.y;
  const int d = threadIdx.x & 63, sg = threadIdx.x >> 6;
  const u16* src = Vp + bh * 131072;
  u16* dst = Vt + bh * 131072;
  const int s0 = st * 64 + sg * 16;
  u16 tmp[16];
  for (int i = 0; i < 16; ++i) tmp[i] = src[(s0 + i) * 64 + d];
  ushort4* o = (ushort4*)(dst + d * 2048 + s0);
  for (int k = 0; k < 4; ++k) {
    ushort4 t4;
    t4.x = tmp[4 * k]; t4.y = tmp[4 * k + 1];
    t4.z = tmp[4 * k + 2]; t4.w = tmp[4 * k + 3];
    o[k] = t4;
  }
}

// ---------------- causal flash attention (swapped-QK, balanced pairs) ----
// Qp,Kp: (B,H,S,D) bf16; Vt: (B,H,D,S) bf16; ctx out: (B*S, 1024) bf16
// grid (16, 32): block x handles q-tiles x and 31-x sequentially -> every
// wave does exactly 33 tile-iterations. No block-level barriers.
__global__ __launch_bounds__(256) void attn_kernel(const u16* __restrict__ Qp,
                                                   const u16* __restrict__ Kp,
                                                   const u16* __restrict__ Vt,
                                                   u16* __restrict__ ctx) {
  const int x = blockIdx.x, bh = blockIdx.y;
  const int tid = threadIdx.x, w = tid >> 6, l = tid & 63;
  const int l4 = l >> 4, l15 = l & 15;
  __shared__ u16 lds_p[4][1024];  // per-wave 16x64 bf16 P tile, swizzled
  char* pw = (char*)lds_p[w];

  const u16* Qbh = Qp + bh * 131072;   // (S, 64)
  const u16* Kbh = Kp + bh * 131072;   // (S, 64)
  const u16* Vbh = Vt + bh * 131072;   // (64, S)
  const int b = bh >> 4, h = bh & 15;
  u16* ctxb = ctx + (size_t)b * 2048 * 1024 + h * 64;

  const float SCALE2 = 0.03125f * 1.44269504f;  // 1/32 * log2(e)
  const float PEN2 = 144269.5f;                 // 100000 * log2(e)
  const int swz = (l15 & 7) << 4;

  for (int half = 0; half < 2; ++half) {
    const int qt = half ? (31 - x) : x;
    const int q0 = qt * 64 + w * 16;

    // Q fragments (B-operand): Q[q0+l15][l4*8 + j], both 32-halves of D=64
    const u16* qb = Qbh + (q0 + l15) * 64 + l4 * 8;
    const bf16x8 bq0 = *(const bf16x8*)(qb);
    const bf16x8 bq1 = *(const bf16x8*)(qb + 32);

    f32x4 zero4 = {0.f, 0.f, 0.f, 0.f};
    f32x4 accO[4];
    for (int g = 0; g < 4; ++g) accO[g] = zero4;
    float m2 = -1.0e30f, lsum = 0.f;

    for (int t2 = 0; t2 <= qt; ++t2) {
      const int kv0 = t2 * 64;
      // ---- K fragments (A-operand) + QK^T (swapped: S^T, q = lane col) --
      const u16* kb = Kbh + (kv0 + l15) * 64 + l4 * 8;
      f32x4 s[4];
      for (int g = 0; g < 4; ++g) {
        bf16x8 kf = *(const bf16x8*)(kb + g * 1024);
        s[g] = __builtin_amdgcn_mfma_f32_16x16x32_bf16(kf, bq0, zero4, 0, 0, 0);
      }
      for (int g = 0; g < 4; ++g) {
        bf16x8 kf = *(const bf16x8*)(kb + g * 1024 + 32);
        s[g] = __builtin_amdgcn_mfma_f32_16x16x32_bf16(kf, bq1, s[g], 0, 0, 0);
      }
      // ---- issue V loads now; consumed after softmax ----
      const u16* vb = Vbh + l15 * 2048 + kv0 + l4 * 8;
      bf16x8 vf[8];
      for (int g = 0; g < 4; ++g) {
        vf[g] = *(const bf16x8*)(vb + g * 16 * 2048);
        vf[g + 4] = *(const bf16x8*)(vb + g * 16 * 2048 + 32);
      }
      // ---- scale (+ causal mask on diagonal tile), base-2 domain ----
      // lane holds S[q=q0+l15][kv = kv0 + g*16 + l4*4 + r]
      float sv[4][4];
      if (t2 == qt) {
        const int q = q0 + l15;
        for (int g = 0; g < 4; ++g)
          for (int r = 0; r < 4; ++r) {
            int kv = kv0 + g * 16 + l4 * 4 + r;
            sv[g][r] = s[g][r] * SCALE2 - (kv > q ? PEN2 : 0.f);
          }
      } else {
        for (int g = 0; g < 4; ++g)
          for (int r = 0; r < 4; ++r) sv[g][r] = s[g][r] * SCALE2;
      }
      // ---- in-lane tile max, then 4-lane column reduce ----
      float mx = sv[0][0];
      for (int g = 0; g < 4; ++g)
        for (int r = 0; r < 4; ++r) mx = fmaxf(mx, sv[g][r]);
      mx = fmaxf(mx, __shfl_xor(mx, 16));
      mx = fmaxf(mx, __shfl_xor(mx, 32));
      const float mnew = fmaxf(m2, mx);
      const float alpha = __builtin_exp2f(m2 - mnew);
      m2 = mnew;
      // ---- p = 2^(s-m), row sum ----
      float p[4][4], rs = 0.f;
      for (int g = 0; g < 4; ++g)
        for (int r = 0; r < 4; ++r) {
          float e = __builtin_exp2f(sv[g][r] - mnew);
          p[g][r] = e;
          rs += e;
        }
      rs += __shfl_xor(rs, 16);
      rs += __shfl_xor(rs, 32);
      lsum = lsum * alpha + rs;
      // ---- rescale accO: alpha for q-row l4*4+r lives in lane l4*4+r ----
      float aR[4];
      for (int r = 0; r < 4; ++r) aR[r] = __shfl(alpha, l4 * 4 + r);
      for (int g = 0; g < 4; ++g) {
        f32x4 t = accO[g];
        t[0] *= aR[0]; t[1] *= aR[1]; t[2] *= aR[2]; t[3] *= aR[3];
        accO[g] = t;
      }
      // ---- P -> bf16 -> LDS (4x ds_write_b64, XOR-swizzled rows) ----
      for (int g = 0; g < 4; ++g) {
        ushort4 q4;
        q4.x = f2bf(p[g][0]); q4.y = f2bf(p[g][1]);
        q4.z = f2bf(p[g][2]); q4.w = f2bf(p[g][3]);
        int byte = (l15 * 128 + g * 32 + l4 * 8) ^ swz;
        *(ushort4*)(pw + byte) = q4;
      }
      // ---- A-fragments of P (2x ds_read_b128) ----
      bf16x8 pa0 = *(const bf16x8*)(pw + ((l15 * 128 + l4 * 16) ^ swz));
      bf16x8 pa1 = *(const bf16x8*)(pw + ((l15 * 128 + 64 + l4 * 16) ^ swz));
      // ---- O += P V ----
      for (int g = 0; g < 4; ++g)
        accO[g] = __builtin_amdgcn_mfma_f32_16x16x32_bf16(pa0, vf[g],
                                                          accO[g], 0, 0, 0);
      for (int g = 0; g < 4; ++g)
        accO[g] = __builtin_amdgcn_mfma_f32_16x16x32_bf16(pa1, vf[g + 4],
                                                          accO[g], 0, 0, 0);
    }
    // ---- epilogue: broadcast 1/lsum to row holders, store ----
    float inv[4];
    for (int r = 0; r < 4; ++r) inv[r] = 1.f / __shfl(lsum, l4 * 4 + r);
    for (int r = 0; r < 4; ++r) {
      u16* orow = ctxb + (size_t)(q0 + l4 * 4 + r) * 1024;
      for (int g = 0; g < 4; ++g)
        orow[g * 16 + l15] = f2bf(accO[g][r] * inv[r]);
    }
  }
}

extern "C" void kernel_launch(void* const* d_in, const int* in_sizes, int n_in,
                              void* d_out, int out_size, void* d_ws,
                              size_t ws_size, hipStream_t stream) {
  (void)in_sizes; (void)n_in; (void)out_size; (void)ws_size;
  const float* key = (const float*)d_in[0];
  const float* query = (const float*)d_in[1];
  const float* value = (const float*)d_in[2];
  const float* Wk = (const float*)d_in[3];
  const float* Wq = (const float*)d_in[4];
  const float* Wv = (const float*)d_in[5];
  const float* Wo = (const float*)d_in[6];

  char* ws = (char*)d_ws;
  u16* keyb = (u16*)(ws + 0);          // 4096x1024 bf16
  u16* qryb = (u16*)(ws + 8388608);
  u16* valb = (u16*)(ws + 16777216);
  u16* Wkb  = (u16*)(ws + 25165824);   // 1024x1024 bf16 each
  u16* Wqb  = (u16*)(ws + 27262976);
  u16* Wvb  = (u16*)(ws + 29360128);
  u16* Wob  = (u16*)(ws + 31457280);
  u16* Kp   = (u16*)(ws + 33554432);   // (B,H,S,D) bf16
  u16* Qp   = (u16*)(ws + 41943040);
  u16* Vp   = (u16*)(ws + 50331648);
  u16* Vt   = (u16*)(ws + 58720256);   // (B,H,D,S) bf16
  u16* ctx  = (u16*)(ws + 67108864);   // (B*S, 1024) bf16

  cvt_kernel<<<4096, 256, 0, stream>>>((const float4*)key, (ushort4*)keyb);
  cvt_kernel<<<4096, 256, 0, stream>>>((const float4*)query, (ushort4*)qryb);
  cvt_kernel<<<4096, 256, 0, stream>>>((const float4*)value, (ushort4*)valb);
  cvt_kernel<<<1024, 256, 0, stream>>>((const float4*)Wk, (ushort4*)Wkb);
  cvt_kernel<<<1024, 256, 0, stream>>>((const float4*)Wq, (ushort4*)Wqb);
  cvt_kernel<<<1024, 256, 0, stream>>>((const float4*)Wv, (ushort4*)Wvb);
  cvt_kernel<<<1024, 256, 0, stream>>>((const float4*)Wo, (ushort4*)Wob);

  gemm_proj<<<dim3(8, 32, 3), 256, 0, stream>>>(keyb, qryb, valb, Wkb, Wqb,
                                                Wvb, Kp, Qp, Vp);
  transpose_v<<<dim3(32, 32), 256, 0, stream>>>(Vp, Vt);
  attn_kernel<<<dim3(16, 32), 256, 0, stream>>>(Qp, Kp, Vt, ctx);
  gemm_out<<<dim3(8, 32), 256, 0, stream>>>(ctx, Wob, (float*)d_out);
}